// Round 7
// baseline (255.173 us; speedup 1.0000x reference)
//
#include <hip/hip_runtime.h>

typedef int i32x4 __attribute__((ext_vector_type(4)));

#define AS1 __attribute__((address_space(1)))
#define AS3 __attribute__((address_space(3)))

// ---------------------------------------------------------------------------
// Quantize kernel (r5/r6 version, VERIFIED). Fully coalesced lane-consecutive
// loads/stores. Blocks [0,M): x rows (fp32 -> i8, scale sx[r] = rowmax/127).
// Blocks [M, M+wB): w int32 (values 0..126, exact) -> i8.
// ---------------------------------------------------------------------------
__global__ __launch_bounds__(256) void quant_kernel(
    const float4* __restrict__ x, const int4* __restrict__ w,
    signed char* __restrict__ xq, signed char* __restrict__ wq,
    float* __restrict__ sx, int M, int Kq) {
  const int tid = threadIdx.x;
  if ((int)blockIdx.x < M) {
    const int r = blockIdx.x;
    float4 v[4];
    #pragma unroll
    for (int j = 0; j < 4; ++j) v[j] = x[(size_t)r * 1024 + j * 256 + tid];
    float m = 0.f;
    #pragma unroll
    for (int j = 0; j < 4; ++j)
      m = fmaxf(m, fmaxf(fmaxf(fabsf(v[j].x), fabsf(v[j].y)),
                         fmaxf(fabsf(v[j].z), fabsf(v[j].w))));
    #pragma unroll
    for (int off = 1; off < 64; off <<= 1) m = fmaxf(m, __shfl_xor(m, off));
    __shared__ float wmax[4];
    if ((tid & 63) == 0) wmax[tid >> 6] = m;
    __syncthreads();
    m = fmaxf(fmaxf(wmax[0], wmax[1]), fmaxf(wmax[2], wmax[3]));
    const float inv = (m > 0.f) ? 127.0f / m : 0.f;
    if (tid == 0) sx[r] = m * (1.0f / 127.0f);
    int* out = (int*)xq;
    #pragma unroll
    for (int j = 0; j < 4; ++j) {
      const int q0 = __float2int_rn(v[j].x * inv) & 255;
      const int q1 = __float2int_rn(v[j].y * inv) & 255;
      const int q2 = __float2int_rn(v[j].z * inv) & 255;
      const int q3 = __float2int_rn(v[j].w * inv) & 255;
      out[(size_t)r * 1024 + j * 256 + tid] = q0 | (q1 << 8) | (q2 << 16) | (q3 << 24);
    }
  } else {
    const int b = blockIdx.x - M;
    int4 v[4];
    #pragma unroll
    for (int j = 0; j < 4; ++j) v[j] = w[(size_t)b * 1024 + j * 256 + tid];
    int* out = (int*)wq;
    #pragma unroll
    for (int j = 0; j < 4; ++j)
      out[(size_t)b * 1024 + j * 256 + tid] =
          (v[j].x & 255) | ((v[j].y & 255) << 8) | ((v[j].z & 255) << 16) | ((v[j].w & 255) << 24);
  }
}

// ---------------------------------------------------------------------------
// C[M][N] = (Aq[M][K] . Bq[N][K]^T) * sx[M] * scaler[N]
//
// Round-7: B OFF LDS. i8 makes the r3 geometry exactly 1:1 LDS:MFMA
// (144KB ~1290cy vs 1306cy MFMA per CU-tile) -> ~50% MfmaUtil hard ceiling,
// which no barrier schedule can beat (rounds 0-3 all flat). Fix: load B
// fragments DIRECT from global into registers (one global_load_dwordx4 per
// frag: 64 lanes x 16B = 16 full 64B lines, 100% utilized, L2-resident),
// double-buffered one tile ahead (bnext/bcur ping-pong, 32 VGPRs).
// LDS keeps A only: per-CU traffic 144KB -> 96KB (~857cy) — MFMA dominant.
//   tile 256(M) x 128(N), 4 waves (2M x 2N), wave tile 128x64, BK=64,
//   mfma_i32_16x16x64_i8, 2 blocks/CU (LDS 48KB, VGPR+AGPR ~244 <= 256).
// A ring: 3-deep, stage t+2 during t (one barrier/tile liveness, verified).
// vmcnt: my asm handles A-staging only (4 loads/tile; end wait vmcnt(4) —
//   all of last tile's <=8 ops are older than this tile's 8, so the count
//   is robust to intra-tile reorder). Compiler inserts its own precise
//   vmcnt for the bcur<-bnext dependency (loads issued a full tile ago).
// Swizzle on A (verified): phys_slot = logical ^ ((row>>1)&3) on both the
//   pre-swizzled global source and the ds_read address -> 0 conflicts.
// T1 XCD swizzle kept (neutral on FETCH, verified r6).
// ---------------------------------------------------------------------------
__global__ __launch_bounds__(256, 2) void gemm_i8_kernel(
    const signed char* __restrict__ A,   // [M][K] i8
    const signed char* __restrict__ B,   // [N][K] i8
    const float* __restrict__ sx,        // [M] x dequant scale
    const float* __restrict__ scaler,    // [N] weight scale
    float* __restrict__ C,               // [M][N] fp32
    int M, int N, int K)
{
  __shared__ signed char sA[3][256 * 64];   // 3 x 16 KB = 48 KB (A only)

  const int tid  = threadIdx.x;
  const int wave = tid >> 6;
  const int lane = tid & 63;

  // T1: XCD-aware bijective swizzle (nwg = 512 = 64*8).
  const int lin = (int)(blockIdx.y * gridDim.x + blockIdx.x);
  const int swz = (lin & 7) * 64 + (lin >> 3);
  const int bm = (swz >> 5) << 8;           // 256-row M tile
  const int bn = (swz & 31) << 7;           // 128-col N tile

  const int wm = (wave >> 1) << 7;   // 0 or 128 : wave's M offset
  const int wn = (wave & 1) << 6;    // 0 or 64  : wave's N offset
  const int l15  = lane & 15;
  const int quad = lane >> 4;

  // A staging (verified): thread t covers row set*64 + (t>>2), phys 16B slot
  // (t&3); logical k-group = (t&3) ^ ((row>>1)&3).
  const int srow = tid >> 2;                      // 0..63
  const int kg = (tid & 3) ^ ((srow >> 1) & 3);
  const signed char* ga = A + (size_t)(bm + srow) * K + kg * 16;
  const size_t rstep = (size_t)64 * K;            // +64 rows per set
  const int ldst = tid * 16;                      // linear LDS dest (4KB/set)

  // A fragment ds_read (verified): row = wm + mi*16 + l15, logical kgroup =
  // quad, phys = quad ^ ((l15>>1)&3).
  const int pk   = (quad ^ ((l15 >> 1) & 3)) << 4;
  const int aoff = (wm + l15) * 64 + pk;    // + mi*1024 per fragment

  // B direct-from-global fragment base: lane reads row bn+wn+ni*16+l15,
  // bytes [t*64 + quad*16, +16). 16B-aligned (K=4096).
  const signed char* gB = B + (size_t)(bn + wn + l15) * K + quad * 16;
  const size_t nstep = (size_t)16 * K;      // +16 rows per ni

  i32x4 acc[8][4] = {};
  i32x4 bcur[4], bnext[4];

  // STAGE_A(tt, sb): 4 global_load_lds — A rows [0,256) in 4 sets of 64.
#define STAGE_A(tt, sb) do { const size_t ko_ = (size_t)(tt) * 64;           \
    __builtin_amdgcn_global_load_lds((AS1 void*)(ga + ko_),             (AS3 void*)(&sA[sb][ldst]),         16, 0, 0); \
    __builtin_amdgcn_global_load_lds((AS1 void*)(ga + ko_ + rstep),     (AS3 void*)(&sA[sb][4096 + ldst]),  16, 0, 0); \
    __builtin_amdgcn_global_load_lds((AS1 void*)(ga + ko_ + 2 * rstep), (AS3 void*)(&sA[sb][8192 + ldst]),  16, 0, 0); \
    __builtin_amdgcn_global_load_lds((AS1 void*)(ga + ko_ + 3 * rstep), (AS3 void*)(&sA[sb][12288 + ldst]), 16, 0, 0); } while (0)

  const int nt = K >> 6;                    // 64 K-tiles

  // Prologue: stage A tiles 0,1 (8 loads) + B frags for tile 0 (4 loads).
  // vmcnt(8): S(0) drained (8 newest = S(1)4 + BF(0)4 may fly).
  STAGE_A(0, 0); STAGE_A(1, 1);
  #pragma unroll
  for (int ni = 0; ni < 4; ++ni) bnext[ni] = *(const i32x4*)(gB + ni * nstep);
  asm volatile("s_waitcnt vmcnt(8)" ::: "memory");
  __builtin_amdgcn_s_barrier();
  __builtin_amdgcn_sched_barrier(0);

  int br = 0;                               // read buf  = t % 3
  int bs = 2;                               // stage buf = (t+2) % 3
  for (int t = 0; t < nt; ++t) {
    const signed char* la = sA[br];

    // Rotate B regs (compiler inserts the precise vmcnt wait here for loads
    // issued a full tile ago — L2 hits, long landed).
    #pragma unroll
    for (int ni = 0; ni < 4; ++ni) bcur[ni] = bnext[ni];
    // Issue next tile's B frags + A staging.
    if (t < nt - 1) {
      #pragma unroll
      for (int ni = 0; ni < 4; ++ni)
        bnext[ni] = *(const i32x4*)(gB + ni * nstep + (size_t)(t + 1) * 64);
    }
    if (t < nt - 2) STAGE_A(t + 2, bs);     // into buf[(t-1)%3] — safe (1 barrier ago)

    i32x4 av[8];
    #pragma unroll
    for (int mi = 0; mi < 8; ++mi) av[mi] = *(const i32x4*)&la[aoff + mi * 1024];

    __builtin_amdgcn_s_setprio(1);
    #pragma unroll
    for (int mi = 0; mi < 8; ++mi)
      #pragma unroll
      for (int ni = 0; ni < 4; ++ni)
        acc[mi][ni] = __builtin_amdgcn_mfma_i32_16x16x64_i8(av[mi], bcur[ni], acc[mi][ni], 0, 0, 0);
    __builtin_amdgcn_s_setprio(0);

    // Tile boundary: guarantee S(t+1) landed (everything older than this
    // tile's <=8 ops drains); keep this tile's staging in flight.
    if (t < nt - 2)        asm volatile("s_waitcnt vmcnt(4)" ::: "memory");
    else if (t == nt - 2)  asm volatile("s_waitcnt vmcnt(0)" ::: "memory");
    if (t < nt - 1) {
      __builtin_amdgcn_s_barrier();
      __builtin_amdgcn_sched_barrier(0);
    }
    br = (br == 2) ? 0 : br + 1;
    bs = (bs == 2) ? 0 : bs + 1;
  }
#undef STAGE_A

  // Epilogue: C/D layout col=lane&15 (N), row=quad*4+reg (M) — dtype-indep.
  #pragma unroll
  for (int mi = 0; mi < 8; ++mi) {
    const int gm0 = bm + wm + mi * 16 + quad * 4;
    float sr[4];
    #pragma unroll
    for (int r = 0; r < 4; ++r) sr[r] = sx[gm0 + r];
    #pragma unroll
    for (int ni = 0; ni < 4; ++ni) {
      const int gn = bn + wn + ni * 16 + l15;
      const float sc = scaler[gn];
      #pragma unroll
      for (int r = 0; r < 4; ++r)
        C[(size_t)(gm0 + r) * N + gn] = (float)acc[mi][ni][r] * sr[r] * sc;
    }
  }
}

extern "C" void kernel_launch(void* const* d_in, const int* in_sizes, int n_in,
                              void* d_out, int out_size, void* d_ws, size_t ws_size,
                              hipStream_t stream) {
  const float* x  = (const float*)d_in[0];          // [B,S,K] fp32
  const int*   w  = (const int*)d_in[1];            // [N,K] int32 (int8 range)
  const float* sc = (const float*)d_in[2];          // [N] fp32
  float* out = (float*)d_out;

  const int N = in_sizes[2];                        // 4096
  const int K = in_sizes[1] / N;                    // 4096
  const int M = in_sizes[0] / K;                    // 4096

  signed char* Aq = (signed char*)d_ws;             // [M][K] i8
  signed char* Bq = Aq + (size_t)M * K;             // [N][K] i8
  float* sx = (float*)(Bq + (size_t)N * K);         // [M] fp32

  const int wBlocks = (N * K) / (256 * 16);         // 16 elems/thread
  quant_kernel<<<M + wBlocks, 256, 0, stream>>>(
      (const float4*)x, (const int4*)w, Aq, Bq, sx, M, K / 16);

  dim3 grid(N / 128, M / 256);
  gemm_i8_kernel<<<grid, 256, 0, stream>>>(Aq, Bq, sx, sc, out, M, N, K);
}